// Round 35
// baseline (64.918 us; speedup 1.0000x reference)
//
#include <hip/hip_runtime.h>
#include <hip/hip_bf16.h>

// x: (B=4, T=5, C=3, H=128, W=128) fp32 ; R=2 ; D = 60 ; N = 4096
#define BB 4
#define TC 15
#define DD 60
#define NN 4096
#define HH 128
#define DP 64
#define KT 128
#define NWAVE 4
#define QT 64
#define NTILES (NN / KT)   // 32
#define NSPLIT 4
#define L2E 1.4426950408889634f

typedef short s8v __attribute__((ext_vector_type(8)));   // 8 x bf16
typedef ushort u4v __attribute__((ext_vector_type(4)));
typedef uint  uu2 __attribute__((ext_vector_type(2)));
typedef float f4v __attribute__((ext_vector_type(4)));
typedef float f2v __attribute__((ext_vector_type(2)));

static __device__ __forceinline__ ushort f2bf_bits(float f) {
    __hip_bfloat16 h = __float2bfloat16(f);
    return *reinterpret_cast<ushort*>(&h);
}
static __device__ __forceinline__ float bf2f(ushort w) { return __uint_as_float((uint)w << 16); }
static __device__ __forceinline__ float bf2f_lo(uint u) { return __uint_as_float(u << 16); }
static __device__ __forceinline__ float bf2f_hi(uint u) { return __uint_as_float(u & 0xFFFF0000u); }

// ---------- K1 (fused): blocks 0..511 = d-parallel prep; blocks 512..527 = Mc.
// NO memset needed: per-block norm max written unconditionally to bmax[512].
__global__ __launch_bounds__(256) void k_prep(const float* __restrict__ x,
                                              ushort* __restrict__ xf2,
                                              ushort* __restrict__ xf_t,
                                              float* __restrict__ rnorm,
                                              float* __restrict__ bmax,
                                              const float* __restrict__ g_w,
                                              const float* __restrict__ g_b,
                                              const float* __restrict__ w_w,
                                              const float* __restrict__ w_b,
                                              float* __restrict__ Mc) {
    if (blockIdx.x >= 512) {                           // ---- Mc blocks ----
        int idx = (blockIdx.x - 512) * 256 + threadIdx.x;
        if (idx < DD * DD) {
            int p = idx / DD, d = idx % DD;
            float acc = 0.f;
            #pragma unroll
            for (int o = 0; o < DD; ++o)
                acc = fmaf(w_w[p * DD + o], g_w[o * DD + d], acc);
            Mc[idx] = acc;
        } else if (idx < DD * DD + DD) {
            int p = idx - DD * DD;
            float acc = w_b[p];
            #pragma unroll
            for (int o = 0; o < DD; ++o)
                acc = fmaf(w_w[p * DD + o], g_b[o], acc);
            Mc[idx] = acc;
        }
        return;
    }
    __shared__ float ssp[8][33];
    int tid = threadIdx.x;
    int pix = tid & 31, j = tid >> 5;                  // d-group j: d = 8j..8j+7
    int n = blockIdx.x * 32 + pix;                     // blocks never cross b (128/batch)
    int b = n >> 12, nn = n & (NN - 1);
    int oh = nn >> 6, ow = nn & 63;
    const float* xb = x + (size_t)b * TC * HH * HH;
    ushort* x2 = xf2 + (size_t)b * DP * NN + nn;
    ushort row[8];
    float ss = 0.f;
    const int nh = (j < 7) ? 4 : 2;                    // j=7: only c1=14 (d 56..59)
    #pragma unroll
    for (int h = 0; h < 4; ++h) {
        if (h < nh) {
            int c1 = 2 * j + (h >> 1), r1 = h & 1;
            f2v v = *(const f2v*)&xb[(c1 * HH + oh * 2 + r1) * HH + ow * 2];
            ushort w0 = f2bf_bits(v[0]), w1 = f2bf_bits(v[1]);
            row[2 * h] = w0; row[2 * h + 1] = w1;
            float f0 = bf2f(w0), f1 = bf2f(w1);
            ss = fmaf(f0, f0, ss);
            ss = fmaf(f1, f1, ss);
            int d0 = 8 * j + 2 * h;
            x2[(size_t)d0 * NN] = w0;
            x2[(size_t)(d0 + 1) * NN] = w1;
        } else {
            row[2 * h] = 0; row[2 * h + 1] = 0;        // xf_t padding d 60..63 = 0
        }
    }
    if (j == 7) {                                      // xf2 special rows
        x2[(size_t)60 * NN] = (ushort)0x3F80;          // ones row -> l accumulator
        x2[(size_t)61 * NN] = 0;
        x2[(size_t)62 * NN] = 0;
        x2[(size_t)63 * NN] = 0;
    }
    *(s8v*)&xf_t[(size_t)n * DP + j * 8] = *(const s8v*)row;

    ssp[j][pix] = ss;
    __syncthreads();
    if (tid < 32) {
        float tot = ssp[0][tid] + ssp[1][tid] + ssp[2][tid] + ssp[3][tid]
                  + ssp[4][tid] + ssp[5][tid] + ssp[6][tid] + ssp[7][tid];
        float norm = sqrtf(tot) * 1.0002f;             // safety margin: m bounds row max
        rnorm[blockIdx.x * 32 + tid] = norm;
        float mv = norm;
        #pragma unroll
        for (int off = 1; off < 32; off <<= 1) mv = fmaxf(mv, __shfl_xor(mv, off));
        if (tid == 0) bmax[blockIdx.x] = mv;           // unconditional write
    }
}

// ---------- K3: flash attention, split-K=4, KT=128 (2x amortization: 8 tiles/block,
// 16 barriers vs 32; 32 MFMA per tile). Swapped-operand QK^T; merged P/PV phases.
// LDS 48KB: K[128][128B] + Xt-tile[64][256B] + P[4 waves][16][256B] -> 3 blocks/CU
// (residency falsified as lever in r19). Z = P.X^T with xf2 row 60 = 1 -> l.
template <int NS>
__global__ __launch_bounds__(256, 2) void k_attn(const ushort* __restrict__ xf_t,
                                                 const ushort* __restrict__ x2_bf, // (B,64,N)
                                                 const float* __restrict__ rnorm,
                                                 const float* __restrict__ bmax,
                                                 ushort* __restrict__ O_bf) {  // (s,b,64,N) bf16
    __shared__ char K_lds[KT * 128];                   // 16 KB
    __shared__ char G_lds[DP * 256];                   // 16 KB (X^T tile, 256B rows)
    __shared__ char P_lds[NWAVE][16 * 256];            // 16 KB (256B rows)

    int p = blockIdx.x;
    int s, b, q0;
    if (NS == NSPLIT) {
        // XCD-aware: xcd = p&7; each XCD pair-half owns one batch (~1MB = L2-hot)
        int xcd = p & 7, slot = p >> 3;                // slot in [0,128)
        b = xcd >> 1;
        s = (xcd & 1) * 2 + (slot >> 6);               // NS=4: 2 splits per xcd-half
        q0 = (slot & 63) * QT;
    } else {
        s = 0;
        b = p >> 6;
        q0 = (p & 63) * QT;
    }
    int tid = threadIdx.x;
    int lane = tid & 63, wv = tid >> 6;
    int r = lane & 15, g = lane >> 4;

    const ushort* Xt = xf_t + (size_t)b * NN * DP;
    const ushort* Gb = x2_bf + (size_t)b * DP * NN;

    int qrow = q0 + wv * 16 + r;
    s8v qa[2];
    qa[0] = *(const s8v*)&Xt[(size_t)qrow * DP + g * 8];
    qa[1] = *(const s8v*)&Xt[(size_t)qrow * DP + 32 + g * 8];

    // batch max from per-block maxima (128 entries, all lanes converge to max)
    float mx = fmaxf(bmax[b * 128 + lane], bmax[b * 128 + 64 + lane]);
    #pragma unroll
    for (int off = 1; off < 64; off <<= 1) mx = fmaxf(mx, __shfl_xor(mx, off));
    // fixed softmax shift: query is lane-fixed (= r) -> ONE scalar
    float nm = -rnorm[b * NN + qrow] * mx * L2E;

    f4v of[4];
    #pragma unroll
    for (int i = 0; i < 4; ++i) of[i] = (f4v){0.f, 0.f, 0.f, 0.f};

    // staging: 256 threads x 4 16B units per buffer (K: 128 rows x 128B;
    // G: 64 rows x 256B). Per-unit rows/offsets are compile-time post-unroll.
    int kwK[4], kwG[4], krK[4], kjK[4], krG[4], kjG[4];
    #pragma unroll
    for (int u = 0; u < 4; ++u) {
        int e = u * 256 + tid;
        krK[u] = e >> 3; kjK[u] = e & 7;
        kwK[u] = (krK[u] * 128 + kjK[u] * 16) ^ ((krK[u] & 7) << 4);
        krG[u] = e >> 4; kjG[u] = e & 15;
        kwG[u] = (krG[u] * 256 + kjG[u] * 16) ^ ((krG[u] & 7) << 4);
    }
    s8v kp[4], gp[4];

    auto stage_regs = [&](int t) {
        int n0 = t * KT;
        #pragma unroll
        for (int u = 0; u < 4; ++u) {
            kp[u] = *(const s8v*)&Xt[(size_t)(n0 + krK[u]) * DP + kjK[u] * 8];
            gp[u] = *(const s8v*)&Gb[(size_t)krG[u] * NN + n0 + kjG[u] * 8];
        }
    };
    auto lds_write = [&]() {
        #pragma unroll
        for (int u = 0; u < 4; ++u) {
            *(s8v*)(K_lds + kwK[u]) = kp[u];
            *(s8v*)(G_lds + kwG[u]) = gp[u];
        }
    };

    const int t0 = s * (NTILES / NS);
    const int tend = t0 + NTILES / NS;
    char* Pw = P_lds[wv];

    stage_regs(t0);
    lds_write();
    __syncthreads();

    #pragma unroll 1
    for (int t = t0; t < tend; ++t) {
        bool more = (t + 1 < tend);
        if (more) stage_regs(t + 1);          // global loads in flight during compute

        // ---- S^T = K.Q^T: 8 key sub-tiles x 2 kb (16 MFMAs) ----
        f4v sf[8];
        #pragma unroll
        for (int i = 0; i < 8; ++i) sf[i] = (f4v){0.f, 0.f, 0.f, 0.f};
        #pragma unroll
        for (int kt2 = 0; kt2 < 8; ++kt2)
            #pragma unroll
            for (int kb = 0; kb < 2; ++kb) {
                int off = (((kt2 * 16 + r) * 128) + kb * 64 + g * 16) ^ ((r & 7) << 4);
                s8v bf = *(const s8v*)(K_lds + off);
                sf[kt2] = __builtin_amdgcn_mfma_f32_16x16x32_bf16(bf, qa[kb], sf[kt2], 0, 0, 0);
            }

        // ---- P (all 128 keys): 32 exp2 -> 8 packed b64 writes (256B P rows) ----
        #pragma unroll
        for (int kt2 = 0; kt2 < 8; ++kt2) {
            uint p0 = __float_as_uint(__builtin_exp2f(fmaf(sf[kt2][0], L2E, nm)));
            uint p1 = __float_as_uint(__builtin_exp2f(fmaf(sf[kt2][1], L2E, nm)));
            uint p2 = __float_as_uint(__builtin_exp2f(fmaf(sf[kt2][2], L2E, nm)));
            uint p3 = __float_as_uint(__builtin_exp2f(fmaf(sf[kt2][3], L2E, nm)));
            uu2 dw = { (p0 >> 16) | (p1 & 0xFFFF0000u),
                       (p2 >> 16) | (p3 & 0xFFFF0000u) };
            int woff = ((r * 256) + 32 * kt2 + 8 * g) ^ ((r & 7) << 4);
            *(uu2*)(Pw + woff) = dw;
        }
        // ---- Z += P.X^T: 4 kb slices x 4 ot (16 MFMAs) ----
        #pragma unroll
        for (int kb = 0; kb < 4; ++kb) {
            int poff = ((r * 256) + kb * 64 + g * 16) ^ ((r & 7) << 4);
            s8v pa = *(const s8v*)(Pw + poff);
            #pragma unroll
            for (int ot = 0; ot < 4; ++ot) {
                int goff = (((ot * 16 + r) * 256) + kb * 64 + g * 16) ^ ((r & 7) << 4);
                s8v gf = *(const s8v*)(G_lds + goff);
                of[ot] = __builtin_amdgcn_mfma_f32_16x16x32_bf16(pa, gf, of[ot], 0, 0, 0);
            }
        }

        if (more) {
            __syncthreads();                  // all waves done reading K/X^T
            lds_write();
            __syncthreads();                  // next tile staged
        }
    }

    // epilogue: unnormalized Z (+ l in col 60); k_cout applies M and divides
    int qb = q0 + wv * 16 + 4 * g;
    ushort* Ob = O_bf + ((size_t)(s * BB + b) * DP) * NN;
    #pragma unroll
    for (int ot = 0; ot < 4; ++ot) {
        int o = ot * 16 + r;
        u4v v = {f2bf_bits(of[ot][0]), f2bf_bits(of[ot][1]),
                 f2bf_bits(of[ot][2]), f2bf_bits(of[ot][3])};
        *(u4v*)&Ob[(size_t)o * NN + qb] = v;                 // coalesced 32B per r-group
    }
}

// ---------- K4 (fused combine+out): phase 1 u32 pixel-pair loads; phase 2
// o-pair f2v loads/stores. Block per 32 pixels, grid BB*128.
template <int NS>
__global__ __launch_bounds__(256) void k_cout(const ushort* __restrict__ O_bf,
                                              const float* __restrict__ Mc,
                                              const float* __restrict__ x,
                                              float* __restrict__ out) {
    __shared__ float ww[DD * DD];                      // 14.4 KB (= M)
    __shared__ float wb[DD];                           //          (= c)
    __shared__ float zlds[32][61];                     // 7.8 KB
    __shared__ float linv[32];

    int b  = blockIdx.x >> 7;                          // grid = BB*128
    int n0 = (blockIdx.x & 127) * 32;
    int tid = threadIdx.x;
    for (int i = tid; i < DD * DD; i += 256) ww[i] = Mc[i];
    if (tid < DD) wb[tid] = Mc[DD * DD + tid];

    // ---- phase 1 (vectorized): pixel pair pp = tid&15 (pixels 2pp, 2pp+1),
    //      o-group tid>>4 handles 4 o's; u32 loads = 2 pixels at once ----
    {
        int pp   = tid & 15;
        int ogrp = tid >> 4;                           // 0..15
        const ushort* Op = O_bf + (size_t)b * DP * NN + n0 + 2 * pp;
        #pragma unroll
        for (int i = 0; i < 4; ++i) {
            int o = ogrp * 4 + i;                      // 0..63
            if (o > DD) continue;                      // o<=60 processed
            float s0 = 0.f, s1 = 0.f;
            #pragma unroll
            for (int ss = 0; ss < NS; ++ss) {
                uint v = *(const uint*)&Op[(size_t)ss * BB * DP * NN + (size_t)o * NN];
                s0 += bf2f_lo(v);
                s1 += bf2f_hi(v);
            }
            if (o < DD) { zlds[2 * pp][o] = s0; zlds[2 * pp + 1][o] = s1; }
            else        { linv[2 * pp] = 1.0f / s0; linv[2 * pp + 1] = 1.0f / s1; }
        }
    }
    __syncthreads();

    // ---- phase 2: 4 o-pairs per thread (o = 2*(8k+ogrp)), f2v load/store ----
    int pix  = tid & 31;
    int ogrp = tid >> 5;                               // 0..7
    int n = n0 + pix;
    float li = linv[pix];
    int oh = n >> 6, ow = n & 63;
    #pragma unroll
    for (int k = 0; k < 4; ++k) {
        int o = 2 * (8 * k + ogrp);                    // even o: 0..62
        if (o < DD) {                                  // covers pairs (0,1)..(58,59)
            float a0 = 0.f, a1 = 0.f;
            #pragma unroll
            for (int d = 0; d < DD; ++d) {
                float z = zlds[pix][d];
                a0 = fmaf(ww[o * DD + d], z, a0);
                a1 = fmaf(ww[(o + 1) * DD + d], z, a1);
            }
            int c1 = o >> 2, r1 = (o >> 1) & 1;        // r2 = 0 then 1 (adjacent xi)
            size_t xi = ((size_t)(b * TC + c1) * HH + 2 * oh + r1) * HH + 2 * ow;
            f2v xv = *(const f2v*)&x[xi];
            f2v res = {fmaf(a0, li, wb[o]) + xv[0], fmaf(a1, li, wb[o + 1]) + xv[1]};
            *(f2v*)&out[xi] = res;
        }
    }
}

extern "C" void kernel_launch(void* const* d_in, const int* in_sizes, int n_in,
                              void* d_out, int out_size, void* d_ws, size_t ws_size,
                              hipStream_t stream) {
    const float* x   = (const float*)d_in[0];
    const float* g_w = (const float*)d_in[1];
    const float* g_b = (const float*)d_in[2];
    const float* w_w = (const float*)d_in[3];
    const float* w_b = (const float*)d_in[4];
    float* out = (float*)d_out;

    char* ws = (char*)d_ws;
    ushort* xf2    = (ushort*)ws;                      // 2,097,152 B (B,64,N)
    ushort* xf_t   = (ushort*)(ws + 2097152);          // 2,097,152 B (B,N,64)
    float*  rnorm  = (float*)(ws + 4194304);           // 65,536 B
    float*  bmax   = (float*)(ws + 4259840);           // 2,048 B (512 per-block maxima)
    float*  Mc     = (float*)(ws + 4261888);           // 16,384 B  (3600 M + 60 c)
    ushort* O_bf   = (ushort*)(ws + 4278272);          // 8,388,608 B (NS=4) -> end 12,666,880
    const size_t SPLIT_NEED = 12666880;

    k_prep<<<528, 256, 0, stream>>>(x, xf2, xf_t, rnorm, bmax,
                                    g_w, g_b, w_w, w_b, Mc);   // blocks 512+ do Mc

    if (ws_size >= SPLIT_NEED) {
        k_attn<NSPLIT><<<NSPLIT * BB * (NN / QT), 256, 0, stream>>>(
            xf_t, xf2, rnorm, bmax, O_bf);
        k_cout<NSPLIT><<<BB * 128, 256, 0, stream>>>(O_bf, Mc, x, out);
    } else {
        k_attn<1><<<BB * (NN / QT), 256, 0, stream>>>(
            xf_t, xf2, rnorm, bmax, O_bf);
        k_cout<1><<<BB * 128, 256, 0, stream>>>(O_bf, Mc, x, out);
    }
}

// Round 36
// 56.650 us; speedup vs baseline: 1.1460x; 1.1460x over previous
//
#include <hip/hip_runtime.h>
#include <hip/hip_bf16.h>

// x: (B=4, T=5, C=3, H=128, W=128) fp32 ; R=2 ; D = 60 ; N = 4096
#define BB 4
#define TC 15
#define DD 60
#define NN 4096
#define HH 128
#define DP 64
#define KT 64
#define NWAVE 4
#define QT 64
#define NTILES 64
#define NSPLIT 4
#define L2E 1.4426950408889634f

typedef short s8v __attribute__((ext_vector_type(8)));   // 8 x bf16
typedef ushort u4v __attribute__((ext_vector_type(4)));
typedef uint  uu2 __attribute__((ext_vector_type(2)));
typedef float f4v __attribute__((ext_vector_type(4)));
typedef float f2v __attribute__((ext_vector_type(2)));

static __device__ __forceinline__ ushort f2bf_bits(float f) {
    __hip_bfloat16 h = __float2bfloat16(f);
    return *reinterpret_cast<ushort*>(&h);
}
static __device__ __forceinline__ float bf2f(ushort w) { return __uint_as_float((uint)w << 16); }
static __device__ __forceinline__ float bf2f_lo(uint u) { return __uint_as_float(u << 16); }
static __device__ __forceinline__ float bf2f_hi(uint u) { return __uint_as_float(u & 0xFFFF0000u); }

// ---------- K1 (fused): blocks 0..511 = d-parallel prep; blocks 512..527 = Mc.
// NO memset needed: per-block norm max written unconditionally to bmax[512]
// (attn reduces its batch's 128 entries itself). Mc: M = w_w.g_w ; c = w_w.g_b + w_b.
__global__ __launch_bounds__(256) void k_prep(const float* __restrict__ x,
                                              ushort* __restrict__ xf2,
                                              ushort* __restrict__ xf_t,
                                              float* __restrict__ rnorm,
                                              float* __restrict__ bmax,
                                              const float* __restrict__ g_w,
                                              const float* __restrict__ g_b,
                                              const float* __restrict__ w_w,
                                              const float* __restrict__ w_b,
                                              float* __restrict__ Mc) {
    if (blockIdx.x >= 512) {                           // ---- Mc blocks ----
        int idx = (blockIdx.x - 512) * 256 + threadIdx.x;
        if (idx < DD * DD) {
            int p = idx / DD, d = idx % DD;
            float acc = 0.f;
            #pragma unroll
            for (int o = 0; o < DD; ++o)
                acc = fmaf(w_w[p * DD + o], g_w[o * DD + d], acc);
            Mc[idx] = acc;
        } else if (idx < DD * DD + DD) {
            int p = idx - DD * DD;
            float acc = w_b[p];
            #pragma unroll
            for (int o = 0; o < DD; ++o)
                acc = fmaf(w_w[p * DD + o], g_b[o], acc);
            Mc[idx] = acc;
        }
        return;
    }
    __shared__ float ssp[8][33];
    int tid = threadIdx.x;
    int pix = tid & 31, j = tid >> 5;                  // d-group j: d = 8j..8j+7
    int n = blockIdx.x * 32 + pix;                     // blocks never cross b (128/batch)
    int b = n >> 12, nn = n & (NN - 1);
    int oh = nn >> 6, ow = nn & 63;
    const float* xb = x + (size_t)b * TC * HH * HH;
    ushort* x2 = xf2 + (size_t)b * DP * NN + nn;
    ushort row[8];
    float ss = 0.f;
    const int nh = (j < 7) ? 4 : 2;                    // j=7: only c1=14 (d 56..59)
    #pragma unroll
    for (int h = 0; h < 4; ++h) {
        if (h < nh) {
            int c1 = 2 * j + (h >> 1), r1 = h & 1;
            f2v v = *(const f2v*)&xb[(c1 * HH + oh * 2 + r1) * HH + ow * 2];
            ushort w0 = f2bf_bits(v[0]), w1 = f2bf_bits(v[1]);
            row[2 * h] = w0; row[2 * h + 1] = w1;
            float f0 = bf2f(w0), f1 = bf2f(w1);
            ss = fmaf(f0, f0, ss);
            ss = fmaf(f1, f1, ss);
            int d0 = 8 * j + 2 * h;
            x2[(size_t)d0 * NN] = w0;
            x2[(size_t)(d0 + 1) * NN] = w1;
        } else {
            row[2 * h] = 0; row[2 * h + 1] = 0;        // xf_t padding d 60..63 = 0
        }
    }
    if (j == 7) {                                      // xf2 special rows
        x2[(size_t)60 * NN] = (ushort)0x3F80;          // ones row -> l accumulator
        x2[(size_t)61 * NN] = 0;
        x2[(size_t)62 * NN] = 0;
        x2[(size_t)63 * NN] = 0;
    }
    *(s8v*)&xf_t[(size_t)n * DP + j * 8] = *(const s8v*)row;

    ssp[j][pix] = ss;
    __syncthreads();
    if (tid < 32) {
        float tot = ssp[0][tid] + ssp[1][tid] + ssp[2][tid] + ssp[3][tid]
                  + ssp[4][tid] + ssp[5][tid] + ssp[6][tid] + ssp[7][tid];
        float norm = sqrtf(tot) * 1.0002f;             // safety margin: m bounds row max
        rnorm[blockIdx.x * 32 + tid] = norm;
        float mv = norm;
        #pragma unroll
        for (int off = 1; off < 32; off <<= 1) mv = fmaxf(mv, __shfl_xor(mv, off));
        if (tid == 0) bmax[blockIdx.x] = mv;           // unconditional write: no init, no atomic
    }
}

// ---------- K3: flash attention, split-K=4, SWAPPED-OPERAND QK^T.
// S^T = mfma(K_frag, Q_frag): lane holds S[query=r][key=16*kt2+4g+reg]; nm scalar.
// Batch max reduced in-kernel from bmax[b*128..+127] (2 loads + 6-step shfl max).
// MERGED phases: ONE P-phase (16 exp2 + 4 packed b64 writes), ONE PV-phase (8 MFMAs).
// Z = P.X^T with xf2 row 60 = 1 -> l. k_cout applies M and divides.
template <int NS>
__global__ __launch_bounds__(256, 2) void k_attn(const ushort* __restrict__ xf_t,
                                                 const ushort* __restrict__ x2_bf, // (B,64,N)
                                                 const float* __restrict__ rnorm,
                                                 const float* __restrict__ bmax,
                                                 ushort* __restrict__ O_bf) {  // (s,b,64,N) bf16
    __shared__ char K_lds[KT * 128];                   // 8 KB
    __shared__ char G_lds[DP * 128];                   // 8 KB (X^T tile)
    __shared__ char P_lds[NWAVE][16 * 128];            // 8 KB

    int p = blockIdx.x;
    int s, b, q0;
    if (NS == NSPLIT) {
        // XCD-aware: xcd = p&7; each XCD pair-half owns one batch (~1MB = L2-hot)
        int xcd = p & 7, slot = p >> 3;                // slot in [0,128)
        b = xcd >> 1;
        s = (xcd & 1) * 2 + (slot >> 6);               // NS=4: 2 splits per xcd-half
        q0 = (slot & 63) * QT;
    } else {
        s = 0;
        b = p >> 6;
        q0 = (p & 63) * QT;
    }
    int tid = threadIdx.x;
    int lane = tid & 63, wv = tid >> 6;
    int r = lane & 15, g = lane >> 4;

    const ushort* Xt = xf_t + (size_t)b * NN * DP;
    const ushort* Gb = x2_bf + (size_t)b * DP * NN;

    int qrow = q0 + wv * 16 + r;
    s8v qa[2];
    qa[0] = *(const s8v*)&Xt[(size_t)qrow * DP + g * 8];
    qa[1] = *(const s8v*)&Xt[(size_t)qrow * DP + 32 + g * 8];

    // batch max from per-block maxima (128 entries, all lanes converge to max)
    float mx = fmaxf(bmax[b * 128 + lane], bmax[b * 128 + 64 + lane]);
    #pragma unroll
    for (int off = 1; off < 64; off <<= 1) mx = fmaxf(mx, __shfl_xor(mx, off));
    // fixed softmax shift: query is lane-fixed (= r) -> ONE scalar
    float nm = -rnorm[b * NN + qrow] * mx * L2E;

    f4v of[4];
    #pragma unroll
    for (int i = 0; i < 4; ++i) of[i] = (f4v){0.f, 0.f, 0.f, 0.f};

    // staging: 256 threads x two 16B units per buffer; row = e>>3, j = e&7
    const int e0 = tid, e1 = 256 + tid;
    const int kr0 = e0 >> 3, kj0 = e0 & 7;             // rows 0..31
    const int kr1 = e1 >> 3, kj1 = e1 & 7;             // rows 32..63
    const int kw0 = (kr0 * 128 + kj0 * 16) ^ ((kr0 & 7) << 4);
    const int kw1 = (kr1 * 128 + kj1 * 16) ^ ((kr1 & 7) << 4);
    s8v kp0, kp1, gp0, gp1;

    auto stage_regs = [&](int t) {
        int n0 = t * KT;
        kp0 = *(const s8v*)&Xt[(size_t)(n0 + kr0) * DP + kj0 * 8];
        kp1 = *(const s8v*)&Xt[(size_t)(n0 + kr1) * DP + kj1 * 8];
        gp0 = *(const s8v*)&Gb[(size_t)kr0 * NN + n0 + kj0 * 8];   // branch-free: 64 rows
        gp1 = *(const s8v*)&Gb[(size_t)kr1 * NN + n0 + kj1 * 8];
    };
    auto lds_write = [&]() {
        *(s8v*)(K_lds + kw0) = kp0;
        *(s8v*)(K_lds + kw1) = kp1;
        *(s8v*)(G_lds + kw0) = gp0;
        *(s8v*)(G_lds + kw1) = gp1;
    };

    const int t0 = s * (NTILES / NS);
    const int tend = t0 + NTILES / NS;
    char* Pw = P_lds[wv];

    stage_regs(t0);
    lds_write();
    __syncthreads();

    #pragma unroll 1
    for (int t = t0; t < tend; ++t) {
        bool more = (t + 1 < tend);
        if (more) stage_regs(t + 1);          // global loads in flight during compute

        // ---- S^T = K.Q^T (swapped operands; same LDS reads) ----
        f4v sf[4];
        #pragma unroll
        for (int i = 0; i < 4; ++i) sf[i] = (f4v){0.f, 0.f, 0.f, 0.f};
        #pragma unroll
        for (int kt2 = 0; kt2 < 4; ++kt2)
            #pragma unroll
            for (int kb = 0; kb < 2; ++kb) {
                int off = (((kt2 * 16 + r) * 128) + kb * 64 + g * 16) ^ ((r & 7) << 4);
                s8v bf = *(const s8v*)(K_lds + off);
                sf[kt2] = __builtin_amdgcn_mfma_f32_16x16x32_bf16(bf, qa[kb], sf[kt2], 0, 0, 0);
            }

        // ---- P (all 64 keys): 16 exp2 -> 4 packed b64 writes ----
        #pragma unroll
        for (int kt2 = 0; kt2 < 4; ++kt2) {
            uint p0 = __float_as_uint(__builtin_exp2f(fmaf(sf[kt2][0], L2E, nm)));
            uint p1 = __float_as_uint(__builtin_exp2f(fmaf(sf[kt2][1], L2E, nm)));
            uint p2 = __float_as_uint(__builtin_exp2f(fmaf(sf[kt2][2], L2E, nm)));
            uint p3 = __float_as_uint(__builtin_exp2f(fmaf(sf[kt2][3], L2E, nm)));
            uu2 dw = { (p0 >> 16) | (p1 & 0xFFFF0000u),
                       (p2 >> 16) | (p3 & 0xFFFF0000u) };
            int woff = ((r * 128) + 32 * kt2 + 8 * g) ^ ((r & 7) << 4);
            *(uu2*)(Pw + woff) = dw;
        }
        // ---- Z += P.X^T (both kb halves; wave-internal LDS is in-order) ----
        #pragma unroll
        for (int kb = 0; kb < 2; ++kb) {
            int poff = ((r * 128) + kb * 64 + g * 16) ^ ((r & 7) << 4);
            s8v pa = *(const s8v*)(Pw + poff);
            #pragma unroll
            for (int ot = 0; ot < 4; ++ot) {
                int goff = (((ot * 16 + r) * 128) + kb * 64 + g * 16) ^ ((r & 7) << 4);
                s8v gf = *(const s8v*)(G_lds + goff);
                of[ot] = __builtin_amdgcn_mfma_f32_16x16x32_bf16(pa, gf, of[ot], 0, 0, 0);
            }
        }

        if (more) {
            __syncthreads();                  // all waves done reading K/X^T
            lds_write();
            __syncthreads();                  // next tile staged
        }
    }

    // epilogue: unnormalized Z (+ l in col 60); k_cout applies M and divides
    int qb = q0 + wv * 16 + 4 * g;
    ushort* Ob = O_bf + ((size_t)(s * BB + b) * DP) * NN;
    #pragma unroll
    for (int ot = 0; ot < 4; ++ot) {
        int o = ot * 16 + r;
        u4v v = {f2bf_bits(of[ot][0]), f2bf_bits(of[ot][1]),
                 f2bf_bits(of[ot][2]), f2bf_bits(of[ot][3])};
        *(u4v*)&Ob[(size_t)o * NN + qb] = v;                 // coalesced 32B per r-group
    }
}

// ---------- K4 (fused combine+out): phase 1 u32 pixel-pair loads; phase 2
// o-pair f2v loads/stores. Block per 32 pixels, grid BB*128.
template <int NS>
__global__ __launch_bounds__(256) void k_cout(const ushort* __restrict__ O_bf,
                                              const float* __restrict__ Mc,
                                              const float* __restrict__ x,
                                              float* __restrict__ out) {
    __shared__ float ww[DD * DD];                      // 14.4 KB (= M)
    __shared__ float wb[DD];                           //          (= c)
    __shared__ float zlds[32][61];                     // 7.8 KB
    __shared__ float linv[32];

    int b  = blockIdx.x >> 7;                          // grid = BB*128
    int n0 = (blockIdx.x & 127) * 32;
    int tid = threadIdx.x;
    for (int i = tid; i < DD * DD; i += 256) ww[i] = Mc[i];
    if (tid < DD) wb[tid] = Mc[DD * DD + tid];

    // ---- phase 1 (vectorized): pixel pair pp = tid&15 (pixels 2pp, 2pp+1),
    //      o-group tid>>4 handles 4 o's; u32 loads = 2 pixels at once ----
    {
        int pp   = tid & 15;
        int ogrp = tid >> 4;                           // 0..15
        const ushort* Op = O_bf + (size_t)b * DP * NN + n0 + 2 * pp;
        #pragma unroll
        for (int i = 0; i < 4; ++i) {
            int o = ogrp * 4 + i;                      // 0..63
            if (o > DD) continue;                      // o<=60 processed
            float s0 = 0.f, s1 = 0.f;
            #pragma unroll
            for (int ss = 0; ss < NS; ++ss) {
                uint v = *(const uint*)&Op[(size_t)ss * BB * DP * NN + (size_t)o * NN];
                s0 += bf2f_lo(v);
                s1 += bf2f_hi(v);
            }
            if (o < DD) { zlds[2 * pp][o] = s0; zlds[2 * pp + 1][o] = s1; }
            else        { linv[2 * pp] = 1.0f / s0; linv[2 * pp + 1] = 1.0f / s1; }
        }
    }
    __syncthreads();

    // ---- phase 2: 4 o-pairs per thread (o = 2*(8k+ogrp)), f2v load/store ----
    int pix  = tid & 31;
    int ogrp = tid >> 5;                               // 0..7
    int n = n0 + pix;
    float li = linv[pix];
    int oh = n >> 6, ow = n & 63;
    #pragma unroll
    for (int k = 0; k < 4; ++k) {
        int o = 2 * (8 * k + ogrp);                    // even o: 0..62
        if (o < DD) {                                  // covers pairs (0,1)..(58,59)
            float a0 = 0.f, a1 = 0.f;
            #pragma unroll
            for (int d = 0; d < DD; ++d) {
                float z = zlds[pix][d];
                a0 = fmaf(ww[o * DD + d], z, a0);
                a1 = fmaf(ww[(o + 1) * DD + d], z, a1);
            }
            int c1 = o >> 2, r1 = (o >> 1) & 1;        // r2 = 0 then 1 (adjacent xi)
            size_t xi = ((size_t)(b * TC + c1) * HH + 2 * oh + r1) * HH + 2 * ow;
            f2v xv = *(const f2v*)&x[xi];
            f2v res = {fmaf(a0, li, wb[o]) + xv[0], fmaf(a1, li, wb[o + 1]) + xv[1]};
            *(f2v*)&out[xi] = res;
        }
    }
}

extern "C" void kernel_launch(void* const* d_in, const int* in_sizes, int n_in,
                              void* d_out, int out_size, void* d_ws, size_t ws_size,
                              hipStream_t stream) {
    const float* x   = (const float*)d_in[0];
    const float* g_w = (const float*)d_in[1];
    const float* g_b = (const float*)d_in[2];
    const float* w_w = (const float*)d_in[3];
    const float* w_b = (const float*)d_in[4];
    float* out = (float*)d_out;

    char* ws = (char*)d_ws;
    ushort* xf2    = (ushort*)ws;                      // 2,097,152 B (B,64,N)
    ushort* xf_t   = (ushort*)(ws + 2097152);          // 2,097,152 B (B,N,64)
    float*  rnorm  = (float*)(ws + 4194304);           // 65,536 B
    float*  bmax   = (float*)(ws + 4259840);           // 2,048 B (512 per-block maxima)
    float*  Mc     = (float*)(ws + 4261888);           // 16,384 B  (3600 M + 60 c)
    ushort* O_bf   = (ushort*)(ws + 4278272);          // 8,388,608 B (NS=4) -> end 12,666,880
    const size_t SPLIT_NEED = 12666880;

    k_prep<<<528, 256, 0, stream>>>(x, xf2, xf_t, rnorm, bmax,
                                    g_w, g_b, w_w, w_b, Mc);   // blocks 512+ do Mc

    if (ws_size >= SPLIT_NEED) {
        k_attn<NSPLIT><<<NSPLIT * BB * (NN / QT), 256, 0, stream>>>(
            xf_t, xf2, rnorm, bmax, O_bf);
        k_cout<NSPLIT><<<BB * 128, 256, 0, stream>>>(O_bf, Mc, x, out);
    } else {
        k_attn<1><<<BB * (NN / QT), 256, 0, stream>>>(
            xf_t, xf2, rnorm, bmax, O_bf);
        k_cout<1><<<BB * 128, 256, 0, stream>>>(O_bf, Mc, x, out);
    }
}